// Round 10
// baseline (782.845 us; speedup 1.0000x reference)
//
#include <hip/hip_runtime.h>
#include <stdint.h>

#define N_ANCH   106392
#define PRE_NMS  6000
#define POST_NMS 1000
#define POOL_CAP 8192
#define NMS_BLKS 94   // 94*64 = 6016 >= 6000
#define SUP_W    96   // padded words per suppression row

static __device__ const int    LV_H[5]      = {128, 64, 32, 16, 8};
static __device__ const int    LV_W[5]      = {208, 104, 52, 26, 13};
static __device__ const int    LV_STRIDE[5] = {4, 8, 16, 32, 64};
static __device__ const int    LV_PIX[5]    = {26624, 6656, 1664, 416, 104};
static __device__ const int    LV_TILE0[6]  = {0, 416, 520, 546, 553, 555};
static __device__ const int    LV_AOFF[6]   = {0, 79872, 99840, 104832, 106080, 106392};
static __device__ const int    GPOFF[6]     = {0, 26624, 33280, 34944, 35360, 35464};
// Base anchors computed with np.round (half-even) semantics, verified by hand.
static __device__ const double BASE_ANCH[5][3][4] = {
  {{-22.,-10.,25.,13.},   {-14.,-14.,17.,17.},    {-10.,-22.,13.,25.}},
  {{-40.,-20.,47.,27.},   {-28.,-28.,35.,35.},    {-20.,-44.,27.,51.}},
  {{-84.,-40.,99.,55.},   {-56.,-56.,71.,71.},    {-36.,-80.,51.,95.}},
  {{-164.,-72.,195.,103.},{-112.,-112.,143.,143.},{-76.,-168.,107.,199.}},
  {{-332.,-152.,395.,215.},{-224.,-224.,287.,287.},{-148.,-328.,211.,391.}}
};

// sortable mappings (monotone): bigger value -> bigger key
__device__ __forceinline__ uint32_t sort32f(float f) {
  uint32_t u = __float_as_uint(f);
  return ((int)u < 0) ? ~u : (u | 0x80000000u);
}
__device__ __forceinline__ uint64_t sort64(double d) {
  uint64_t u = (uint64_t)__double_as_longlong(d);
  return ((long long)u < 0) ? ~u : (u | 0x8000000000000000ull);
}

// ---------------- f64 effective weights, 2-stage ----------------
// comb inline: j<3 -> sw[3+j][c]-sw[j][c]; 3<=j<15 -> bw[j-3][c]
__device__ __forceinline__ double combf(const float* sw, const float* bw, int c, int j) {
  if (j < 3) return (double)sw[(3 + j) * 512 + c] - (double)sw[j * 512 + c];
  return (double)bw[(j - 3) * 512 + c];
}

__global__ __launch_bounds__(256) void k_weff_part(const float* __restrict__ cw,
                                                   const float* __restrict__ sw,
                                                   const float* __restrict__ bw,
                                                   double* __restrict__ Wpart) {
  int chunk = blockIdx.x / 9;            // 16 chunks of 32 channels
  int tb = blockIdx.x % 9;               // 9 t-blocks of 256
  int t = tb * 256 + threadIdx.x;        // 0..2303
  int c0 = chunk * 32;
  double acc[15];
#pragma unroll
  for (int j = 0; j < 15; ++j) acc[j] = 0.0;
#pragma unroll 1
  for (int c = c0; c < c0 + 32; ++c) {
    double v = (double)cw[c * 2304 + t];
#pragma unroll
    for (int j = 0; j < 15; ++j) acc[j] += v * combf(sw, bw, c, j);
  }
  double* o = Wpart + (((size_t)chunk * 2304 + t) << 4);
#pragma unroll
  for (int j = 0; j < 15; ++j) o[j] = acc[j];
  o[15] = 0.0;
}

// blocks 0..8: Weff[t][j] = sum over chunks; also emit f32 screen weights w3.
// block 9: fb f64 + fb32.
__global__ __launch_bounds__(256) void k_weff_fin(const double* __restrict__ Wpart,
                                                  const float* __restrict__ cb,
                                                  const float* __restrict__ sb,
                                                  const float* __restrict__ bb,
                                                  const float* __restrict__ sw,
                                                  const float* __restrict__ bw,
                                                  double* __restrict__ Weff,
                                                  double* __restrict__ fb,
                                                  float4* __restrict__ w3,
                                                  float* __restrict__ fb32) {
  if (blockIdx.x == 9) {
    __shared__ double ps[15][16];
    int tid = threadIdx.x;
    if (tid < 240) {
      int j = tid >> 4, part = tid & 15;
      double s = 0.0;
      for (int c = part * 32; c < part * 32 + 32; ++c)
        s += (double)cb[c] * combf(sw, bw, c, j);
      ps[j][part] = s;
    }
    __syncthreads();
    if (tid < 15) {
      double s = 0.0;
#pragma unroll
      for (int part = 0; part < 16; ++part) s += ps[tid][part];  // fixed order
      s += (tid < 3) ? ((double)sb[3 + tid] - (double)sb[tid]) : (double)bb[tid - 3];
      fb[tid] = s;
      if (tid < 3) fb32[tid] = (float)s;
    }
    if (tid == 15) fb32[3] = 0.f;
    return;
  }
  int t = blockIdx.x * 256 + threadIdx.x;
  double acc[15];
#pragma unroll
  for (int j = 0; j < 15; ++j) acc[j] = 0.0;
#pragma unroll 1
  for (int chunk = 0; chunk < 16; ++chunk) {
    const double* p = Wpart + (((size_t)chunk * 2304 + t) << 4);
#pragma unroll
    for (int j = 0; j < 15; ++j) acc[j] += p[j];
  }
  double* o = Weff + ((size_t)t << 4);
#pragma unroll
  for (int j = 0; j < 15; ++j) o[j] = acc[j];
  o[15] = 0.0;
  float4 wf;
  wf.x = (float)acc[0]; wf.y = (float)acc[1]; wf.z = (float)acc[2]; wf.w = 0.f;
  w3[t] = wf;
}

// ---------------- f32 screening pass: 3 logits/pixel + histogram ----------------
__device__ __forceinline__ void load9(float v[9], const float* __restrict__ ib,
                                      const bool rok[3], const bool cok[3],
                                      const int roff[3]) {
#pragma unroll
  for (int ky = 0; ky < 3; ++ky)
#pragma unroll
    for (int kx = 0; kx < 3; ++kx)
      v[ky * 3 + kx] = (rok[ky] && cok[kx]) ? ib[roff[ky] + kx] : 0.0f;
}

__global__ __launch_bounds__(256) void k_fast(
    const float* __restrict__ p0, const float* __restrict__ p1,
    const float* __restrict__ p2, const float* __restrict__ p3,
    const float* __restrict__ p4,
    const float4* __restrict__ w3, const float* __restrict__ fb32,
    float* __restrict__ logits32, uint32_t* __restrict__ hist) {
  __shared__ float4 w3s[2304];       // 36.9 KB, LDS-resident weights
  __shared__ float red[4][64][3];
  int tid = threadIdx.x, wv = tid >> 6, ln = tid & 63;
  for (int i = tid; i < 2304; i += 256) w3s[i] = w3[i];
  int t = blockIdx.x;
  int L = 0;
  while (L < 4 && t >= LV_TILE0[L + 1]) ++L;
  const float* inL = (L == 0) ? p0 : (L == 1) ? p1 : (L == 2) ? p2 : (L == 3) ? p3 : p4;
  int H = LV_H[L], W = LV_W[L], HW = H * W, PIX = LV_PIX[L];
  int pix = (t - LV_TILE0[L]) * 64 + ln;
  bool valid = pix < PIX;
  if (!valid) pix = PIX - 1;
  int h = pix / W, w = pix % W;
  bool rok[3], cok[3];
  int roff[3];
#pragma unroll
  for (int ky = 0; ky < 3; ++ky) {
    int iy = h + ky - 1;
    rok[ky] = (iy >= 0 && iy < H);
    roff[ky] = iy * W + w - 1;
  }
#pragma unroll
  for (int kx = 0; kx < 3; ++kx) {
    int ix = w + kx - 1;
    cok[kx] = (ix >= 0 && ix < W);
  }
  __syncthreads();
  float a0 = 0.f, a1 = 0.f, a2 = 0.f;
  int ci0 = wv * 64;
  const float* ib = inL + ci0 * HW;
#pragma unroll 1
  for (int ci = ci0; ci < ci0 + 64; ++ci, ib += HW) {
    float v[9];
    load9(v, ib, rok, cok, roff);
    const float4* wr = w3s + ci * 9;
#pragma unroll
    for (int t9 = 0; t9 < 9; ++t9) {
      float4 wt = wr[t9];                  // broadcast ds_read_b128
      float vv = v[t9];
      a0 += vv * wt.x; a1 += vv * wt.y; a2 += vv * wt.z;
    }
  }
  red[wv][ln][0] = a0; red[wv][ln][1] = a1; red[wv][ln][2] = a2;
  __syncthreads();
  if (wv == 0 && valid) {
    int gbase = LV_AOFF[L] + pix * 3;
#pragma unroll
    for (int a = 0; a < 3; ++a) {
      float f = (red[0][ln][a] + red[1][ln][a]) + (red[2][ln][a] + red[3][ln][a]);
      f += fb32[a];
      logits32[gbase + a] = f;
      atomicAdd(&hist[sort32f(f) >> 16], 1u);
    }
  }
}

// ---------------- edge finder (with 2-bin safety margin) ----------------
__global__ __launch_bounds__(1024) void k_edge(const uint32_t* __restrict__ hist,
                                               uint32_t* __restrict__ cnts) {
  __shared__ uint32_t cs[1024];
  __shared__ uint32_t g_grp, g_suf;
  int t = threadIdx.x, wv = t >> 6, ln = t & 63;
#pragma unroll 4
  for (int r = 0; r < 64; ++r) {
    int g = r * 16 + wv;
    uint32_t x = hist[g * 64 + ln];
#pragma unroll
    for (int off = 32; off > 0; off >>= 1) x += __shfl_down(x, off);
    if (ln == 0) cs[g] = x;
  }
  __syncthreads();
  for (int off = 1; off < 1024; off <<= 1) {
    uint32_t v = cs[t] + ((t + off < 1024) ? cs[t + off] : 0u);
    __syncthreads();
    cs[t] = v;
    __syncthreads();
  }
  uint32_t sufnext = (t < 1023) ? cs[t + 1] : 0u;
  if (cs[t] >= PRE_NMS && sufnext < PRE_NMS) {   // unique t
    g_grp = (uint32_t)t;
    g_suf = sufnext;
  }
  __syncthreads();
  if (t < 64) {   // wave 0: refine edge within the winning 64-bin group
    uint32_t grp = g_grp, suf = g_suf;
    uint32_t x = hist[grp * 64 + t];
    uint32_t S = x;
#pragma unroll
    for (int off = 1; off < 64; off <<= 1) {
      uint32_t y = __shfl_down(S, off);
      if (t + off < 64) S += y;
    }
    unsigned long long mask = __ballot(suf + S >= PRE_NMS);
    int hi = 63 - (int)__clzll(mask);
    if (t == hi) {
      uint32_t e = grp * 64 + (uint32_t)hi;
      cnts[1] = (e > 2) ? e - 2 : 0;     // -2 bin margin: f32 superset of f64 top-k
    }
  }
}

// ---------------- pool compaction (f32 screen) ----------------
__global__ __launch_bounds__(256) void k_compact(const float* __restrict__ logits32,
                                                 uint32_t* __restrict__ cnts,
                                                 uint32_t* __restrict__ alist) {
  int i = blockIdx.x * 256 + threadIdx.x;
  if (i >= N_ANCH) return;
  if ((sort32f(logits32[i]) >> 16) >= cnts[1]) {
    uint32_t pos = atomicAdd(&cnts[0], 1u);
    if (pos < POOL_CAP) alist[pos] = (uint32_t)i;
  }
}

// ---------------- f64 refine: exact logit + deltas + sort key ----------------
__global__ __launch_bounds__(256) void k_refine(
    const float* __restrict__ p0, const float* __restrict__ p1,
    const float* __restrict__ p2, const float* __restrict__ p3,
    const float* __restrict__ p4,
    const double* __restrict__ Weff, const double* __restrict__ fb,
    const uint32_t* __restrict__ alist, const uint32_t* __restrict__ cnts,
    double* __restrict__ logits, double* __restrict__ deltas,
    uint64_t* __restrict__ pkey) {
  __shared__ double red[4][64][5];
  int tid = threadIdx.x, wv = tid >> 6, ln = tid & 63;
  int cnt = (int)cnts[0];
  if (cnt > POOL_CAP) cnt = POOL_CAP;
  int base = blockIdx.x * 64;
  if (base >= cnt) return;                 // uniform early-exit
  int slot = base + ln;
  if (slot >= cnt) slot = cnt - 1;         // dup tail (benign same-value writes)
  int gi = (int)alist[slot];
  int gpix = gi / 3, a = gi - gpix * 3;
  int L = 0;
  while (L < 4 && gpix >= GPOFF[L + 1]) ++L;
  int pix = gpix - GPOFF[L];
  const float* inL = (L == 0) ? p0 : (L == 1) ? p1 : (L == 2) ? p2 : (L == 3) ? p3 : p4;
  int H = LV_H[L], W = LV_W[L], HW = H * W;
  int h = pix / W, w = pix % W;
  bool rok[3], cok[3];
  int roff[3];
#pragma unroll
  for (int ky = 0; ky < 3; ++ky) {
    int iy = h + ky - 1;
    rok[ky] = (iy >= 0 && iy < H);
    roff[ky] = iy * W + w - 1;
  }
#pragma unroll
  for (int kx = 0; kx < 3; ++kx) {
    int ix = w + kx - 1;
    cok[kx] = (ix >= 0 && ix < W);
  }
  double sc = 0.0, d0 = 0.0, d1 = 0.0, d2 = 0.0, d3 = 0.0;
  int js = a, jd = 3 + 4 * a;
  int ci0 = wv * 64;
  const float* ib = inL + ci0 * HW;
#pragma unroll 1
  for (int ci = ci0; ci < ci0 + 64; ++ci, ib += HW) {
    float v[9];
    load9(v, ib, rok, cok, roff);
    const double* wr = Weff + ((size_t)ci * 144);
#pragma unroll
    for (int t9 = 0; t9 < 9; ++t9) {
      double vd = (double)v[t9];
      const double* wt = wr + t9 * 16;
      sc += vd * wt[js];
      d0 += vd * wt[jd + 0];
      d1 += vd * wt[jd + 1];
      d2 += vd * wt[jd + 2];
      d3 += vd * wt[jd + 3];
    }
  }
  red[wv][ln][0] = sc;
  red[wv][ln][1] = d0; red[wv][ln][2] = d1;
  red[wv][ln][3] = d2; red[wv][ln][4] = d3;
  __syncthreads();
  if (wv == 0) {
    double f[5];
#pragma unroll
    for (int j = 0; j < 5; ++j)
      f[j] = red[0][ln][j] + red[1][ln][j] + red[2][ln][j] + red[3][ln][j];
    double lg = f[0] + fb[js];
    logits[gi] = lg;
    deltas[gi * 4 + 0] = f[1] + fb[jd + 0];
    deltas[gi * 4 + 1] = f[2] + fb[jd + 1];
    deltas[gi * 4 + 2] = f[3] + fb[jd + 2];
    deltas[gi * 4 + 3] = f[4] + fb[jd + 3];
    // top-47 bits of sortable f64 logit; low 17 bits inverted index ->
    // rank-descending breaks score ties by ascending index (top_k semantics)
    pkey[slot] = (sort64(lg) & ~0x1FFFFull) | (uint64_t)(0x1FFFFu - (uint32_t)gi);
  }
}

// ---------------- 2D rank-by-counting: 32 i-tiles x 16 j-chunks ----------------
// rank32[e] += #{j in chunk : pkey[j] > pkey[e]}  (u32 atomics: exact, commutative)
__global__ __launch_bounds__(256) void k_rank_cnt(const uint32_t* __restrict__ cnts,
                                                  const uint64_t* __restrict__ pkey,
                                                  uint32_t* __restrict__ rank32) {
  __shared__ uint64_t lk[512];
  int t = threadIdx.x;
  int cnt = (int)cnts[0];
  if (cnt > POOL_CAP) cnt = POOL_CAP;
  int it = blockIdx.x >> 4, jc = blockIdx.x & 15;
  int e = it * 256 + t;
  int c0 = jc * 512;
  if (it * 256 >= cnt || c0 >= cnt) return;   // uniform early-exit
  int lim = cnt - c0; if (lim > 512) lim = 512;
  for (int i = t; i < 512; i += 256) lk[i] = (i < lim) ? pkey[c0 + i] : 0ull;
  __syncthreads();
  bool active = e < cnt;
  uint64_t mykey = active ? pkey[e] : ~0ull;   // ~0 counts nothing
  int r = 0;
#pragma unroll 8
  for (int j = 0; j < 512; ++j) r += (lk[j] > mykey) ? 1 : 0;
  if (active && r) atomicAdd(&rank32[e], (uint32_t)r);
}

// ---------------- scatter by rank + box decode ----------------
__global__ __launch_bounds__(256) void k_scatter(const uint32_t* __restrict__ cnts,
                                                 const uint64_t* __restrict__ pkey,
                                                 const uint32_t* __restrict__ rank32,
                                                 const double* __restrict__ logits,
                                                 const double* __restrict__ deltas,
                                                 const float* __restrict__ im_info,
                                                 double* __restrict__ ss,
                                                 double* __restrict__ sbx,
                                                 float4* __restrict__ bxf,
                                                 float* __restrict__ areaf) {
  int t = threadIdx.x;
  int cnt = (int)cnts[0];
  if (cnt > POOL_CAP) cnt = POOL_CAP;
  int e = blockIdx.x * 256 + t;
  if (blockIdx.x * 256 >= cnt) return;     // uniform
  if (e >= cnt) return;
  int rank = (int)rank32[e];
  if (rank >= PRE_NMS) return;
  uint64_t mykey = pkey[e];
  int gi = 0x1FFFF - (int)(mykey & 0x1FFFFull);
  int L = 0;
  while (L < 4 && gi >= LV_AOFF[L + 1]) ++L;
  int rel = gi - LV_AOFF[L];
  int pix = rel / 3, a = rel % 3;
  int W = LV_W[L];
  int h = pix / W, w = pix % W;
  double imW1 = (double)im_info[1] - 1.0;
  double imH1 = (double)im_info[0] - 1.0;
  double shx = (double)(w * LV_STRIDE[L]), shy = (double)(h * LV_STRIDE[L]);
  double ax1 = BASE_ANCH[L][a][0] + shx, ay1 = BASE_ANCH[L][a][1] + shy;
  double ax2 = BASE_ANCH[L][a][2] + shx, ay2 = BASE_ANCH[L][a][3] + shy;
  double dx = deltas[gi * 4 + 0], dy = deltas[gi * 4 + 1];
  double dw = deltas[gi * 4 + 2], dh = deltas[gi * 4 + 3];
  double wa = ax2 - ax1 + 1.0, ha = ay2 - ay1 + 1.0;
  double cx = ax1 + 0.5 * wa, cy = ay1 + 0.5 * ha;
  double pcx = dx * wa + cx, pcy = dy * ha + cy;
  double pw = exp(dw) * wa, ph = exp(dh) * ha;
  double x1 = fmin(fmax(pcx - 0.5 * pw, 0.0), imW1);
  double y1 = fmin(fmax(pcy - 0.5 * ph, 0.0), imH1);
  double x2 = fmin(fmax(pcx + 0.5 * pw, 0.0), imW1);
  double y2 = fmin(fmax(pcy + 0.5 * ph, 0.0), imH1);
  ss[rank] = 1.0 / (1.0 + exp(-logits[gi]));
  sbx[rank * 4 + 0] = x1; sbx[rank * 4 + 1] = y1;
  sbx[rank * 4 + 2] = x2; sbx[rank * 4 + 3] = y2;
  float4 bf;
  bf.x = (float)x1; bf.y = (float)y1; bf.z = (float)x2; bf.w = (float)y2;
  bxf[rank] = bf;
  areaf[rank] = (float)((x2 - x1 + 1.0) * (y2 - y1 + 1.0));
}

// ---------------- exact f64 IoU decision (reference semantics) ----------------
__device__ __forceinline__ bool iou_gt(const double* A, const double* B) {
  double areaA = (A[2] - A[0] + 1.0) * (A[3] - A[1] + 1.0);
  double areaB = (B[2] - B[0] + 1.0) * (B[3] - B[1] + 1.0);
  double xx1 = fmax(A[0], B[0]), yy1 = fmax(A[1], B[1]);
  double xx2 = fmin(A[2], B[2]), yy2 = fmin(A[3], B[3]);
  double iw = fmax(0.0, xx2 - xx1 + 1.0), ih = fmax(0.0, yy2 - yy1 + 1.0);
  double inter = iw * ih;
  return inter > 0.7 * (areaA + areaB - inter);
}

// ---------------- suppression matrix build (upper triangle) ----------------
// Sup[r][w] bit jj set  <=>  IoU(box r, box w*64+jj) > 0.7, for j > r.
// f32 prefilter with +-4.0 absolute margin on (inter - 0.7*union); f64 confirm
// in the gray zone -> decisions identical to pure f64. Rows/cols >= PRE_NMS
// may read unwritten (poisoned) staging rows; their bits are masked in k_scan.
__global__ __launch_bounds__(256) void k_build(const double* __restrict__ sbx,
                                               const float4* __restrict__ bxf,
                                               const float* __restrict__ areaf,
                                               uint64_t* __restrict__ Sup) {
  __shared__ float cbx[256][5];
  __shared__ float rbx[64][5];
  int blk = blockIdx.x;
  int rtile = blk / 24, ctile = blk % 24;   // 94 x 24
  int t = threadIdx.x, q = t >> 6, ln = t & 63;
  int r = rtile * 64 + ln;
  int w = ctile * 4 + q;                    // word 0..95
  {
    int c = ctile * 256 + t;
    float4 b;
    float ar;
    if (c < NMS_BLKS * 64) { b = bxf[c]; ar = areaf[c]; }
    else { b.x = b.y = b.z = b.w = 0.f; ar = 0.f; }
    cbx[t][0] = b.x; cbx[t][1] = b.y; cbx[t][2] = b.z; cbx[t][3] = b.w; cbx[t][4] = ar;
    if (t < 64) {
      int rr = rtile * 64 + t;
      float4 rb = bxf[rr];
      rbx[t][0] = rb.x; rbx[t][1] = rb.y; rbx[t][2] = rb.z; rbx[t][3] = rb.w;
      rbx[t][4] = areaf[rr];
    }
  }
  __syncthreads();
  uint64_t bits = 0ull;
  int j0 = w * 64;
  if (w < NMS_BLKS && j0 + 63 > r) {
    float ax1 = rbx[ln][0], ay1 = rbx[ln][1], ax2 = rbx[ln][2], ay2 = rbx[ln][3];
    float aar = rbx[ln][4];
#pragma unroll 4
    for (int jj = 0; jj < 64; ++jj) {
      int j = j0 + jj;
      if (j <= r) continue;
      int cl = q * 64 + jj;
      float iw = fminf(ax2, cbx[cl][2]) - fmaxf(ax1, cbx[cl][0]) + 1.f;
      float ih = fminf(ay2, cbx[cl][3]) - fmaxf(ay1, cbx[cl][1]) + 1.f;
      float inter = fmaxf(iw, 0.f) * fmaxf(ih, 0.f);
      float d = inter - 0.7f * (aar + cbx[cl][4] - inter);
      bool sup;
      if (d > 4.0f) sup = true;
      else if (d < -4.0f) sup = false;
      else sup = iou_gt(sbx + (size_t)r * 4, sbx + (size_t)j * 4);  // rare
      if (sup) bits |= 1ull << jj;
    }
  }
  Sup[(size_t)r * SUP_W + w] = bits;
}

// ---------------- wave-resident bit-parallel greedy NMS scan ----------------
// Whole suppressed-state (94 u64 words) lives in 2 registers per lane of wave
// 0 (lane w holds words w and w+64). Zero barriers / LDS in the loop; each
// kept row is read exactly once (coalesced).
__global__ __launch_bounds__(256) void k_scan(const uint64_t* __restrict__ Sup,
                                              const double* __restrict__ ss,
                                              const double* __restrict__ sbx,
                                              float* __restrict__ out) {
  __shared__ uint16_t keep[POST_NMS];
  __shared__ int s_kcnt;
  int t = threadIdx.x, wv = t >> 6, ln = t & 63;
  if (wv == 0) {
    uint64_t supw0 = 0ull, supw1 = 0ull;       // running suppressed words
    uint64_t nrow = Sup[(size_t)ln * SUP_W];   // prefetch block 0 diagonal
    int kcnt = 0;
    for (int b = 0; b < NMS_BLKS && kcnt < POST_NMS; ++b) {
      uint64_t myrow = nrow & ~((2ull << ln) - 1ull);
      if (b + 1 < NMS_BLKS)
        nrow = Sup[(size_t)((b + 1) * 64 + ln) * SUP_W + (b + 1)];
      uint64_t ext = (b < 64) ? __shfl(supw0, b) : __shfl(supw1, b - 64);
      int base = b * 64;
      if (base + 63 >= PRE_NMS) {
        int v = PRE_NMS - base;                // 48 for the tail block
        ext |= ~((1ull << v) - 1ull);
      }
      uint64_t avail = ~ext;
      uint64_t kp = 0ull;                      // uniform across lanes
      int lim = POST_NMS - kcnt, nk = 0;
      while (avail && nk < lim) {
        int i2 = __ffsll((unsigned long long)avail) - 1;
        kp |= 1ull << i2;
        ++nk;
        uint64_t row = __shfl(myrow, i2);
        avail &= ~row;
        avail &= ~(1ull << i2);
      }
      if ((kp >> ln) & 1ull) {
        int pos = kcnt + __popcll(kp & ((1ull << ln) - 1ull));
        keep[pos] = (uint16_t)(base + ln);
      }
      kcnt += nk;
      // OR the newly kept rows into the register-resident state.
      // Lane ln reads words ln and 64+ln of each kept row -> coalesced.
      uint64_t kpi = kp;
      while (kpi) {
        int j = __ffsll((unsigned long long)kpi) - 1;
        kpi &= kpi - 1;
        const uint64_t* rp = Sup + (size_t)(base + j) * SUP_W;
        supw0 |= rp[ln];
        if (ln < NMS_BLKS - 64) supw1 |= rp[64 + ln];
      }
    }
    if (ln == 0) s_kcnt = kcnt;
  }
  __syncthreads();
  int KF = s_kcnt;
  for (int r = t; r < POST_NMS; r += 256) {
    float* o = out + r * 6;
    if (r < KF) {
      int p = keep[r];
      o[0] = 0.f;
      o[1] = (float)sbx[p * 4 + 0];
      o[2] = (float)sbx[p * 4 + 1];
      o[3] = (float)sbx[p * 4 + 2];
      o[4] = (float)sbx[p * 4 + 3];
      o[5] = (float)ss[p];
    } else {
#pragma unroll
      for (int c = 0; c < 6; ++c) o[c] = 0.f;
    }
  }
}

// ---------------- host launch ----------------
extern "C" void kernel_launch(void* const* d_in, const int* in_sizes, int n_in,
                              void* d_out, int out_size, void* d_ws, size_t ws_size,
                              hipStream_t stream) {
  const float* p0 = (const float*)d_in[0];
  const float* p1 = (const float*)d_in[1];
  const float* p2 = (const float*)d_in[2];
  const float* p3 = (const float*)d_in[3];
  const float* p4 = (const float*)d_in[4];
  const float* im_info = (const float*)d_in[5];
  const float* cw = (const float*)d_in[6];
  const float* cb = (const float*)d_in[7];
  const float* sw = (const float*)d_in[8];
  const float* sb = (const float*)d_in[9];
  const float* bw = (const float*)d_in[10];
  const float* bb = (const float*)d_in[11];
  char* ws = (char*)d_ws;
  // ws layout (bytes):
  uint32_t* hist    = (uint32_t*)(ws + 0);         // 65536 u32 -> 262144
  uint32_t* cnts    = (uint32_t*)(ws + 262144);    // [0]=pool [1]=edge -> 262208
  double*   fb      = (double*)  (ws + 262208);    // 16 f64 -> 262336
  float*    fb32    = (float*)   (ws + 262336);    // 4 f32  -> 262352
  double*   logits  = (double*)  (ws + 262352);    // 106392 f64 -> 1113488
  double*   deltas  = (double*)  (ws + 1113488);   // 425568 f64 -> 4518032
  float*    logits32= (float*)   (ws + 4518032);   // 106392 f32 -> 4943600
  float4*   w3      = (float4*)  (ws + 4943600);   // 2304 float4 -> 4980464
  double*   Weff    = (double*)  (ws + 4980464);   // 2304*16 f64 -> 5275376
  double*   Wpart   = (double*)  (ws + 5275376);   // 16*2304*16 f64 -> 9993968
  uint32_t* alist   = (uint32_t*)(ws + 9993968);   // 8192 u32 -> 10026736
  double*   ssort   = (double*)  (ws + 10026736);  // 6016 f64 -> 10074864
  double*   sbx     = (double*)  (ws + 10074864);  // 6016*4 f64 -> 10267376
  float4*   bxf     = (float4*)  (ws + 10267376);  // 6016 float4 -> 10363632
  float*    areaf   = (float*)   (ws + 10363632);  // 6016 f32 -> 10387696
  uint64_t* Sup     = (uint64_t*)(ws + 10387696);  // 6016*96 u64 -> 15007984
  uint64_t* pkey    = (uint64_t*)(ws + 15007984);  // 8192 u64 -> 15073520
  uint32_t* rank32  = (uint32_t*)(ws + 15073520);  // 8192 u32 -> 15106288
  float* out = (float*)d_out;

  hipMemsetAsync(ws, 0, 262208, stream);             // hist + counters
  hipMemsetAsync(rank32, 0, 32768, stream);          // rank accumulators
  k_weff_part<<<144, 256, 0, stream>>>(cw, sw, bw, Wpart);
  k_weff_fin<<<10, 256, 0, stream>>>(Wpart, cb, sb, bb, sw, bw, Weff, fb, w3, fb32);
  k_fast<<<555, 256, 0, stream>>>(p0, p1, p2, p3, p4, w3, fb32, logits32, hist);
  k_edge<<<1, 1024, 0, stream>>>(hist, cnts);
  k_compact<<<416, 256, 0, stream>>>(logits32, cnts, alist);
  k_refine<<<128, 256, 0, stream>>>(p0, p1, p2, p3, p4, Weff, fb, alist, cnts,
                                    logits, deltas, pkey);
  k_rank_cnt<<<512, 256, 0, stream>>>(cnts, pkey, rank32);
  k_scatter<<<32, 256, 0, stream>>>(cnts, pkey, rank32, logits, deltas, im_info,
                                    ssort, sbx, bxf, areaf);
  k_build<<<94 * 24, 256, 0, stream>>>(sbx, bxf, areaf, Sup);
  k_scan<<<1, 256, 0, stream>>>(Sup, ssort, sbx, out);
}

// Round 11
// 577.660 us; speedup vs baseline: 1.3552x; 1.3552x over previous
//
#include <hip/hip_runtime.h>
#include <stdint.h>

#define N_ANCH   106392
#define PRE_NMS  6000
#define POST_NMS 1000
#define POOL_CAP 8192
#define NMS_BLKS 94   // 94*64 = 6016 >= 6000
#define SUP_W    96   // padded words per suppression row

static __device__ const int    LV_H[5]      = {128, 64, 32, 16, 8};
static __device__ const int    LV_W[5]      = {208, 104, 52, 26, 13};
static __device__ const int    LV_STRIDE[5] = {4, 8, 16, 32, 64};
static __device__ const int    LV_PIX[5]    = {26624, 6656, 1664, 416, 104};
static __device__ const int    LV_TILE0[6]  = {0, 416, 520, 546, 553, 555};
static __device__ const int    LV_AOFF[6]   = {0, 79872, 99840, 104832, 106080, 106392};
static __device__ const int    GPOFF[6]     = {0, 26624, 33280, 34944, 35360, 35464};
// Base anchors computed with np.round (half-even) semantics, verified by hand.
static __device__ const double BASE_ANCH[5][3][4] = {
  {{-22.,-10.,25.,13.},   {-14.,-14.,17.,17.},    {-10.,-22.,13.,25.}},
  {{-40.,-20.,47.,27.},   {-28.,-28.,35.,35.},    {-20.,-44.,27.,51.}},
  {{-84.,-40.,99.,55.},   {-56.,-56.,71.,71.},    {-36.,-80.,51.,95.}},
  {{-164.,-72.,195.,103.},{-112.,-112.,143.,143.},{-76.,-168.,107.,199.}},
  {{-332.,-152.,395.,215.},{-224.,-224.,287.,287.},{-148.,-328.,211.,391.}}
};

// sortable mappings (monotone): bigger value -> bigger key
__device__ __forceinline__ uint32_t sort32f(float f) {
  uint32_t u = __float_as_uint(f);
  return ((int)u < 0) ? ~u : (u | 0x80000000u);
}
__device__ __forceinline__ uint64_t sort64(double d) {
  uint64_t u = (uint64_t)__double_as_longlong(d);
  return ((long long)u < 0) ? ~u : (u | 0x8000000000000000ull);
}

// ---------------- f64 effective weights, 2-stage ----------------
// comb inline: j<3 -> sw[3+j][c]-sw[j][c]; 3<=j<15 -> bw[j-3][c]
__device__ __forceinline__ double combf(const float* sw, const float* bw, int c, int j) {
  if (j < 3) return (double)sw[(3 + j) * 512 + c] - (double)sw[j * 512 + c];
  return (double)bw[(j - 3) * 512 + c];
}

__global__ __launch_bounds__(256) void k_weff_part(const float* __restrict__ cw,
                                                   const float* __restrict__ sw,
                                                   const float* __restrict__ bw,
                                                   double* __restrict__ Wpart) {
  int chunk = blockIdx.x / 9;            // 16 chunks of 32 channels
  int tb = blockIdx.x % 9;               // 9 t-blocks of 256
  int t = tb * 256 + threadIdx.x;        // 0..2303
  int c0 = chunk * 32;
  double acc[15];
#pragma unroll
  for (int j = 0; j < 15; ++j) acc[j] = 0.0;
#pragma unroll 1
  for (int c = c0; c < c0 + 32; ++c) {
    double v = (double)cw[c * 2304 + t];
#pragma unroll
    for (int j = 0; j < 15; ++j) acc[j] += v * combf(sw, bw, c, j);
  }
  double* o = Wpart + (((size_t)chunk * 2304 + t) << 4);
#pragma unroll
  for (int j = 0; j < 15; ++j) o[j] = acc[j];
  o[15] = 0.0;
}

// blocks 0..8: Weff[t][j] = sum over chunks; also emit f32 screen weights w3.
// block 9: fb f64 + fb32.
__global__ __launch_bounds__(256) void k_weff_fin(const double* __restrict__ Wpart,
                                                  const float* __restrict__ cb,
                                                  const float* __restrict__ sb,
                                                  const float* __restrict__ bb,
                                                  const float* __restrict__ sw,
                                                  const float* __restrict__ bw,
                                                  double* __restrict__ Weff,
                                                  double* __restrict__ fb,
                                                  float4* __restrict__ w3,
                                                  float* __restrict__ fb32) {
  if (blockIdx.x == 9) {
    __shared__ double ps[15][16];
    int tid = threadIdx.x;
    if (tid < 240) {
      int j = tid >> 4, part = tid & 15;
      double s = 0.0;
      for (int c = part * 32; c < part * 32 + 32; ++c)
        s += (double)cb[c] * combf(sw, bw, c, j);
      ps[j][part] = s;
    }
    __syncthreads();
    if (tid < 15) {
      double s = 0.0;
#pragma unroll
      for (int part = 0; part < 16; ++part) s += ps[tid][part];  // fixed order
      s += (tid < 3) ? ((double)sb[3 + tid] - (double)sb[tid]) : (double)bb[tid - 3];
      fb[tid] = s;
      if (tid < 3) fb32[tid] = (float)s;
    }
    if (tid == 15) fb32[3] = 0.f;
    return;
  }
  int t = blockIdx.x * 256 + threadIdx.x;
  double acc[15];
#pragma unroll
  for (int j = 0; j < 15; ++j) acc[j] = 0.0;
#pragma unroll 1
  for (int chunk = 0; chunk < 16; ++chunk) {
    const double* p = Wpart + (((size_t)chunk * 2304 + t) << 4);
#pragma unroll
    for (int j = 0; j < 15; ++j) acc[j] += p[j];
  }
  double* o = Weff + ((size_t)t << 4);
#pragma unroll
  for (int j = 0; j < 15; ++j) o[j] = acc[j];
  o[15] = 0.0;
  float4 wf;
  wf.x = (float)acc[0]; wf.y = (float)acc[1]; wf.z = (float)acc[2]; wf.w = 0.f;
  w3[t] = wf;
}

// ---------------- f32 screening pass: 3 logits/pixel + histogram ----------------
__device__ __forceinline__ void load9(float v[9], const float* __restrict__ ib,
                                      const bool rok[3], const bool cok[3],
                                      const int roff[3]) {
#pragma unroll
  for (int ky = 0; ky < 3; ++ky)
#pragma unroll
    for (int kx = 0; kx < 3; ++kx)
      v[ky * 3 + kx] = (rok[ky] && cok[kx]) ? ib[roff[ky] + kx] : 0.0f;
}

__global__ __launch_bounds__(256) void k_fast(
    const float* __restrict__ p0, const float* __restrict__ p1,
    const float* __restrict__ p2, const float* __restrict__ p3,
    const float* __restrict__ p4,
    const float4* __restrict__ w3, const float* __restrict__ fb32,
    float* __restrict__ logits32, uint32_t* __restrict__ hist) {
  __shared__ float4 w3s[2304];       // 36.9 KB, LDS-resident weights
  __shared__ float red[4][64][3];
  int tid = threadIdx.x, wv = tid >> 6, ln = tid & 63;
  for (int i = tid; i < 2304; i += 256) w3s[i] = w3[i];
  int t = blockIdx.x;
  int L = 0;
  while (L < 4 && t >= LV_TILE0[L + 1]) ++L;
  const float* inL = (L == 0) ? p0 : (L == 1) ? p1 : (L == 2) ? p2 : (L == 3) ? p3 : p4;
  int H = LV_H[L], W = LV_W[L], HW = H * W, PIX = LV_PIX[L];
  int pix = (t - LV_TILE0[L]) * 64 + ln;
  bool valid = pix < PIX;
  if (!valid) pix = PIX - 1;
  int h = pix / W, w = pix % W;
  bool rok[3], cok[3];
  int roff[3];
#pragma unroll
  for (int ky = 0; ky < 3; ++ky) {
    int iy = h + ky - 1;
    rok[ky] = (iy >= 0 && iy < H);
    roff[ky] = iy * W + w - 1;
  }
#pragma unroll
  for (int kx = 0; kx < 3; ++kx) {
    int ix = w + kx - 1;
    cok[kx] = (ix >= 0 && ix < W);
  }
  __syncthreads();
  float a0 = 0.f, a1 = 0.f, a2 = 0.f;
  int ci0 = wv * 64;
  const float* ib = inL + ci0 * HW;
#pragma unroll 1
  for (int ci = ci0; ci < ci0 + 64; ++ci, ib += HW) {
    float v[9];
    load9(v, ib, rok, cok, roff);
    const float4* wr = w3s + ci * 9;
#pragma unroll
    for (int t9 = 0; t9 < 9; ++t9) {
      float4 wt = wr[t9];                  // broadcast ds_read_b128
      float vv = v[t9];
      a0 += vv * wt.x; a1 += vv * wt.y; a2 += vv * wt.z;
    }
  }
  red[wv][ln][0] = a0; red[wv][ln][1] = a1; red[wv][ln][2] = a2;
  __syncthreads();
  if (wv == 0 && valid) {
    int gbase = LV_AOFF[L] + pix * 3;
#pragma unroll
    for (int a = 0; a < 3; ++a) {
      float f = (red[0][ln][a] + red[1][ln][a]) + (red[2][ln][a] + red[3][ln][a]);
      f += fb32[a];
      logits32[gbase + a] = f;
      atomicAdd(&hist[sort32f(f) >> 16], 1u);
    }
  }
}

// ---------------- edge finder (with 2-bin safety margin) ----------------
__global__ __launch_bounds__(1024) void k_edge(const uint32_t* __restrict__ hist,
                                               uint32_t* __restrict__ cnts) {
  __shared__ uint32_t cs[1024];
  __shared__ uint32_t g_grp, g_suf;
  int t = threadIdx.x, wv = t >> 6, ln = t & 63;
#pragma unroll 4
  for (int r = 0; r < 64; ++r) {
    int g = r * 16 + wv;
    uint32_t x = hist[g * 64 + ln];
#pragma unroll
    for (int off = 32; off > 0; off >>= 1) x += __shfl_down(x, off);
    if (ln == 0) cs[g] = x;
  }
  __syncthreads();
  for (int off = 1; off < 1024; off <<= 1) {
    uint32_t v = cs[t] + ((t + off < 1024) ? cs[t + off] : 0u);
    __syncthreads();
    cs[t] = v;
    __syncthreads();
  }
  uint32_t sufnext = (t < 1023) ? cs[t + 1] : 0u;
  if (cs[t] >= PRE_NMS && sufnext < PRE_NMS) {   // unique t
    g_grp = (uint32_t)t;
    g_suf = sufnext;
  }
  __syncthreads();
  if (t < 64) {   // wave 0: refine edge within the winning 64-bin group
    uint32_t grp = g_grp, suf = g_suf;
    uint32_t x = hist[grp * 64 + t];
    uint32_t S = x;
#pragma unroll
    for (int off = 1; off < 64; off <<= 1) {
      uint32_t y = __shfl_down(S, off);
      if (t + off < 64) S += y;
    }
    unsigned long long mask = __ballot(suf + S >= PRE_NMS);
    int hi = 63 - (int)__clzll(mask);
    if (t == hi) {
      uint32_t e = grp * 64 + (uint32_t)hi;
      cnts[1] = (e > 2) ? e - 2 : 0;     // -2 bin margin: f32 superset of f64 top-k
    }
  }
}

// ---------------- pool compaction (f32 screen) ----------------
__global__ __launch_bounds__(256) void k_compact(const float* __restrict__ logits32,
                                                 uint32_t* __restrict__ cnts,
                                                 uint32_t* __restrict__ alist) {
  int i = blockIdx.x * 256 + threadIdx.x;
  if (i >= N_ANCH) return;
  if ((sort32f(logits32[i]) >> 16) >= cnts[1]) {
    uint32_t pos = atomicAdd(&cnts[0], 1u);
    if (pos < POOL_CAP) alist[pos] = (uint32_t)i;
  }
}

// ---------------- f64 refine: exact logit + deltas + sort key ----------------
__global__ __launch_bounds__(256) void k_refine(
    const float* __restrict__ p0, const float* __restrict__ p1,
    const float* __restrict__ p2, const float* __restrict__ p3,
    const float* __restrict__ p4,
    const double* __restrict__ Weff, const double* __restrict__ fb,
    const uint32_t* __restrict__ alist, const uint32_t* __restrict__ cnts,
    double* __restrict__ logits, double* __restrict__ deltas,
    uint64_t* __restrict__ pkey) {
  __shared__ double red[4][64][5];
  int tid = threadIdx.x, wv = tid >> 6, ln = tid & 63;
  int cnt = (int)cnts[0];
  if (cnt > POOL_CAP) cnt = POOL_CAP;
  int base = blockIdx.x * 64;
  if (base >= cnt) return;                 // uniform early-exit
  int slot = base + ln;
  if (slot >= cnt) slot = cnt - 1;         // dup tail (benign same-value writes)
  int gi = (int)alist[slot];
  int gpix = gi / 3, a = gi - gpix * 3;
  int L = 0;
  while (L < 4 && gpix >= GPOFF[L + 1]) ++L;
  int pix = gpix - GPOFF[L];
  const float* inL = (L == 0) ? p0 : (L == 1) ? p1 : (L == 2) ? p2 : (L == 3) ? p3 : p4;
  int H = LV_H[L], W = LV_W[L], HW = H * W;
  int h = pix / W, w = pix % W;
  bool rok[3], cok[3];
  int roff[3];
#pragma unroll
  for (int ky = 0; ky < 3; ++ky) {
    int iy = h + ky - 1;
    rok[ky] = (iy >= 0 && iy < H);
    roff[ky] = iy * W + w - 1;
  }
#pragma unroll
  for (int kx = 0; kx < 3; ++kx) {
    int ix = w + kx - 1;
    cok[kx] = (ix >= 0 && ix < W);
  }
  double sc = 0.0, d0 = 0.0, d1 = 0.0, d2 = 0.0, d3 = 0.0;
  int js = a, jd = 3 + 4 * a;
  int ci0 = wv * 64;
  const float* ib = inL + ci0 * HW;
#pragma unroll 1
  for (int ci = ci0; ci < ci0 + 64; ++ci, ib += HW) {
    float v[9];
    load9(v, ib, rok, cok, roff);
    const double* wr = Weff + ((size_t)ci * 144);
#pragma unroll
    for (int t9 = 0; t9 < 9; ++t9) {
      double vd = (double)v[t9];
      const double* wt = wr + t9 * 16;
      sc += vd * wt[js];
      d0 += vd * wt[jd + 0];
      d1 += vd * wt[jd + 1];
      d2 += vd * wt[jd + 2];
      d3 += vd * wt[jd + 3];
    }
  }
  red[wv][ln][0] = sc;
  red[wv][ln][1] = d0; red[wv][ln][2] = d1;
  red[wv][ln][3] = d2; red[wv][ln][4] = d3;
  __syncthreads();
  if (wv == 0) {
    double f[5];
#pragma unroll
    for (int j = 0; j < 5; ++j)
      f[j] = red[0][ln][j] + red[1][ln][j] + red[2][ln][j] + red[3][ln][j];
    double lg = f[0] + fb[js];
    logits[gi] = lg;
    deltas[gi * 4 + 0] = f[1] + fb[jd + 0];
    deltas[gi * 4 + 1] = f[2] + fb[jd + 1];
    deltas[gi * 4 + 2] = f[3] + fb[jd + 2];
    deltas[gi * 4 + 3] = f[4] + fb[jd + 3];
    // top-47 bits of sortable f64 logit; low 17 bits inverted index ->
    // rank-descending breaks score ties by ascending index (top_k semantics)
    pkey[slot] = (sort64(lg) & ~0x1FFFFull) | (uint64_t)(0x1FFFFu - (uint32_t)gi);
  }
}

// ---------------- 2D rank-by-counting: 32 i-tiles x 16 j-chunks ----------------
// rank32[e] += #{j in chunk : pkey[j] > pkey[e]}  (u32 atomics: exact, commutative)
__global__ __launch_bounds__(256) void k_rank_cnt(const uint32_t* __restrict__ cnts,
                                                  const uint64_t* __restrict__ pkey,
                                                  uint32_t* __restrict__ rank32) {
  __shared__ uint64_t lk[512];
  int t = threadIdx.x;
  int cnt = (int)cnts[0];
  if (cnt > POOL_CAP) cnt = POOL_CAP;
  int it = blockIdx.x >> 4, jc = blockIdx.x & 15;
  int e = it * 256 + t;
  int c0 = jc * 512;
  if (it * 256 >= cnt || c0 >= cnt) return;   // uniform early-exit
  int lim = cnt - c0; if (lim > 512) lim = 512;
  for (int i = t; i < 512; i += 256) lk[i] = (i < lim) ? pkey[c0 + i] : 0ull;
  __syncthreads();
  bool active = e < cnt;
  uint64_t mykey = active ? pkey[e] : ~0ull;   // ~0 counts nothing
  int r = 0;
#pragma unroll 8
  for (int j = 0; j < 512; ++j) r += (lk[j] > mykey) ? 1 : 0;
  if (active && r) atomicAdd(&rank32[e], (uint32_t)r);
}

// ---------------- scatter by rank + box decode ----------------
__global__ __launch_bounds__(256) void k_scatter(const uint32_t* __restrict__ cnts,
                                                 const uint64_t* __restrict__ pkey,
                                                 const uint32_t* __restrict__ rank32,
                                                 const double* __restrict__ logits,
                                                 const double* __restrict__ deltas,
                                                 const float* __restrict__ im_info,
                                                 double* __restrict__ ss,
                                                 double* __restrict__ sbx,
                                                 float4* __restrict__ bxf,
                                                 float* __restrict__ areaf) {
  int t = threadIdx.x;
  int cnt = (int)cnts[0];
  if (cnt > POOL_CAP) cnt = POOL_CAP;
  int e = blockIdx.x * 256 + t;
  if (blockIdx.x * 256 >= cnt) return;     // uniform
  if (e >= cnt) return;
  int rank = (int)rank32[e];
  if (rank >= PRE_NMS) return;
  uint64_t mykey = pkey[e];
  int gi = 0x1FFFF - (int)(mykey & 0x1FFFFull);
  int L = 0;
  while (L < 4 && gi >= LV_AOFF[L + 1]) ++L;
  int rel = gi - LV_AOFF[L];
  int pix = rel / 3, a = rel % 3;
  int W = LV_W[L];
  int h = pix / W, w = pix % W;
  double imW1 = (double)im_info[1] - 1.0;
  double imH1 = (double)im_info[0] - 1.0;
  double shx = (double)(w * LV_STRIDE[L]), shy = (double)(h * LV_STRIDE[L]);
  double ax1 = BASE_ANCH[L][a][0] + shx, ay1 = BASE_ANCH[L][a][1] + shy;
  double ax2 = BASE_ANCH[L][a][2] + shx, ay2 = BASE_ANCH[L][a][3] + shy;
  double dx = deltas[gi * 4 + 0], dy = deltas[gi * 4 + 1];
  double dw = deltas[gi * 4 + 2], dh = deltas[gi * 4 + 3];
  double wa = ax2 - ax1 + 1.0, ha = ay2 - ay1 + 1.0;
  double cx = ax1 + 0.5 * wa, cy = ay1 + 0.5 * ha;
  double pcx = dx * wa + cx, pcy = dy * ha + cy;
  double pw = exp(dw) * wa, ph = exp(dh) * ha;
  double x1 = fmin(fmax(pcx - 0.5 * pw, 0.0), imW1);
  double y1 = fmin(fmax(pcy - 0.5 * ph, 0.0), imH1);
  double x2 = fmin(fmax(pcx + 0.5 * pw, 0.0), imW1);
  double y2 = fmin(fmax(pcy + 0.5 * ph, 0.0), imH1);
  ss[rank] = 1.0 / (1.0 + exp(-logits[gi]));
  sbx[rank * 4 + 0] = x1; sbx[rank * 4 + 1] = y1;
  sbx[rank * 4 + 2] = x2; sbx[rank * 4 + 3] = y2;
  float4 bf;
  bf.x = (float)x1; bf.y = (float)y1; bf.z = (float)x2; bf.w = (float)y2;
  bxf[rank] = bf;
  areaf[rank] = (float)((x2 - x1 + 1.0) * (y2 - y1 + 1.0));
}

// ---------------- exact f64 IoU decision (reference semantics) ----------------
__device__ __forceinline__ bool iou_gt(const double* A, const double* B) {
  double areaA = (A[2] - A[0] + 1.0) * (A[3] - A[1] + 1.0);
  double areaB = (B[2] - B[0] + 1.0) * (B[3] - B[1] + 1.0);
  double xx1 = fmax(A[0], B[0]), yy1 = fmax(A[1], B[1]);
  double xx2 = fmin(A[2], B[2]), yy2 = fmin(A[3], B[3]);
  double iw = fmax(0.0, xx2 - xx1 + 1.0), ih = fmax(0.0, yy2 - yy1 + 1.0);
  double inter = iw * ih;
  return inter > 0.7 * (areaA + areaB - inter);
}

// ---------------- suppression matrix build (upper triangle) ----------------
// Sup[r][w] bit jj set  <=>  IoU(box r, box w*64+jj) > 0.7, for j > r.
// f32 prefilter with +-4.0 absolute margin on (inter - 0.7*union); f64 confirm
// in the gray zone -> decisions identical to pure f64. Rows/cols >= PRE_NMS
// may read unwritten (poisoned) staging rows; their bits are masked in k_scan.
__global__ __launch_bounds__(256) void k_build(const double* __restrict__ sbx,
                                               const float4* __restrict__ bxf,
                                               const float* __restrict__ areaf,
                                               uint64_t* __restrict__ Sup) {
  __shared__ float cbx[256][5];
  __shared__ float rbx[64][5];
  int blk = blockIdx.x;
  int rtile = blk / 24, ctile = blk % 24;   // 94 x 24
  int t = threadIdx.x, q = t >> 6, ln = t & 63;
  int r = rtile * 64 + ln;
  int w = ctile * 4 + q;                    // word 0..95
  {
    int c = ctile * 256 + t;
    float4 b;
    float ar;
    if (c < NMS_BLKS * 64) { b = bxf[c]; ar = areaf[c]; }
    else { b.x = b.y = b.z = b.w = 0.f; ar = 0.f; }
    cbx[t][0] = b.x; cbx[t][1] = b.y; cbx[t][2] = b.z; cbx[t][3] = b.w; cbx[t][4] = ar;
    if (t < 64) {
      int rr = rtile * 64 + t;
      float4 rb = bxf[rr];
      rbx[t][0] = rb.x; rbx[t][1] = rb.y; rbx[t][2] = rb.z; rbx[t][3] = rb.w;
      rbx[t][4] = areaf[rr];
    }
  }
  __syncthreads();
  uint64_t bits = 0ull;
  int j0 = w * 64;
  if (w < NMS_BLKS && j0 + 63 > r) {
    float ax1 = rbx[ln][0], ay1 = rbx[ln][1], ax2 = rbx[ln][2], ay2 = rbx[ln][3];
    float aar = rbx[ln][4];
#pragma unroll 4
    for (int jj = 0; jj < 64; ++jj) {
      int j = j0 + jj;
      if (j <= r) continue;
      int cl = q * 64 + jj;
      float iw = fminf(ax2, cbx[cl][2]) - fmaxf(ax1, cbx[cl][0]) + 1.f;
      float ih = fminf(ay2, cbx[cl][3]) - fmaxf(ay1, cbx[cl][1]) + 1.f;
      float inter = fmaxf(iw, 0.f) * fmaxf(ih, 0.f);
      float d = inter - 0.7f * (aar + cbx[cl][4] - inter);
      bool sup;
      if (d > 4.0f) sup = true;
      else if (d < -4.0f) sup = false;
      else sup = iou_gt(sbx + (size_t)r * 4, sbx + (size_t)j * 4);  // rare
      if (sup) bits |= 1ull << jj;
    }
  }
  Sup[(size_t)r * SUP_W + w] = bits;
}

// ---------------- wave-resident bit-parallel greedy NMS scan ----------------
// Whole suppressed-state (94 u64 words) lives in 2 registers per lane of wave
// 0. Zero barriers in the loop. OR phase issues 16 rows x 2 words of
// INDEPENDENT loads per batch before any use -> ~16 latencies overlap
// (R10's one-at-a-time chain serialized ~1000 x ~900 cyc = the 395 us bug).
__global__ __launch_bounds__(256) void k_scan(const uint64_t* __restrict__ Sup,
                                              const double* __restrict__ ss,
                                              const double* __restrict__ sbx,
                                              float* __restrict__ out) {
  __shared__ uint16_t keep[POST_NMS];
  __shared__ int s_kcnt;
  int t = threadIdx.x, wv = t >> 6, ln = t & 63;
  if (wv == 0) {
    uint64_t supw0 = 0ull, supw1 = 0ull;       // running suppressed words
    uint64_t nrow = Sup[(size_t)ln * SUP_W];   // prefetch block 0 diagonal
    int kcnt = 0;
    bool w1ok = ln < (NMS_BLKS - 64);
    for (int b = 0; b < NMS_BLKS; ++b) {
      uint64_t myrow = nrow & ~((2ull << ln) - 1ull);
      if (b + 1 < NMS_BLKS)
        nrow = Sup[(size_t)((b + 1) * 64 + ln) * SUP_W + (b + 1)];
      uint64_t ext = (b < 64) ? __shfl(supw0, b) : __shfl(supw1, b - 64);
      int base = b * 64;
      if (base + 63 >= PRE_NMS) {
        int v = PRE_NMS - base;                // 48 for the tail block
        ext |= ~((1ull << v) - 1ull);
      }
      uint64_t avail = ~ext;
      uint64_t kp = 0ull;                      // uniform across lanes
      int lim = POST_NMS - kcnt, nk = 0;
      while (avail && nk < lim) {
        int i2 = __ffsll((unsigned long long)avail) - 1;
        kp |= 1ull << i2;
        ++nk;
        uint64_t row = __shfl(myrow, i2);
        avail &= ~row;
        avail &= ~(1ull << i2);
      }
      if ((kp >> ln) & 1ull) {
        int pos = kcnt + __popcll(kp & ((1ull << ln) - 1ull));
        keep[pos] = (uint16_t)(base + ln);
      }
      kcnt += nk;
      if (kcnt >= POST_NMS || b + 1 >= NMS_BLKS) break;  // OR phase useless
      // Batched OR: extract up to 16 row indices (register-resident via full
      // unroll), issue all 32 independent loads, then fold.
      uint64_t kpi = kp;
      while (kpi) {
        int rows[16];
#pragma unroll
        for (int u = 0; u < 16; ++u) {
          rows[u] = -1;
          if (kpi) {
            rows[u] = base + __ffsll((unsigned long long)kpi) - 1;
            kpi &= kpi - 1;
          }
        }
        uint64_t v0[16], v1[16];
#pragma unroll
        for (int u = 0; u < 16; ++u) {
          v0[u] = 0ull; v1[u] = 0ull;
          if (rows[u] >= 0) {
            const uint64_t* rp = Sup + (size_t)rows[u] * SUP_W;
            v0[u] = rp[ln];
            if (w1ok) v1[u] = rp[64 + ln];
          }
        }
#pragma unroll
        for (int u = 0; u < 16; ++u) { supw0 |= v0[u]; supw1 |= v1[u]; }
      }
    }
    if (ln == 0) s_kcnt = kcnt;
  }
  __syncthreads();
  int KF = s_kcnt;
  for (int r = t; r < POST_NMS; r += 256) {
    float* o = out + r * 6;
    if (r < KF) {
      int p = keep[r];
      o[0] = 0.f;
      o[1] = (float)sbx[p * 4 + 0];
      o[2] = (float)sbx[p * 4 + 1];
      o[3] = (float)sbx[p * 4 + 2];
      o[4] = (float)sbx[p * 4 + 3];
      o[5] = (float)ss[p];
    } else {
#pragma unroll
      for (int c = 0; c < 6; ++c) o[c] = 0.f;
    }
  }
}

// ---------------- host launch ----------------
extern "C" void kernel_launch(void* const* d_in, const int* in_sizes, int n_in,
                              void* d_out, int out_size, void* d_ws, size_t ws_size,
                              hipStream_t stream) {
  const float* p0 = (const float*)d_in[0];
  const float* p1 = (const float*)d_in[1];
  const float* p2 = (const float*)d_in[2];
  const float* p3 = (const float*)d_in[3];
  const float* p4 = (const float*)d_in[4];
  const float* im_info = (const float*)d_in[5];
  const float* cw = (const float*)d_in[6];
  const float* cb = (const float*)d_in[7];
  const float* sw = (const float*)d_in[8];
  const float* sb = (const float*)d_in[9];
  const float* bw = (const float*)d_in[10];
  const float* bb = (const float*)d_in[11];
  char* ws = (char*)d_ws;
  // ws layout (bytes):
  uint32_t* hist    = (uint32_t*)(ws + 0);         // 65536 u32 -> 262144
  uint32_t* cnts    = (uint32_t*)(ws + 262144);    // [0]=pool [1]=edge -> 262208
  double*   fb      = (double*)  (ws + 262208);    // 16 f64 -> 262336
  float*    fb32    = (float*)   (ws + 262336);    // 4 f32  -> 262352
  double*   logits  = (double*)  (ws + 262352);    // 106392 f64 -> 1113488
  double*   deltas  = (double*)  (ws + 1113488);   // 425568 f64 -> 4518032
  float*    logits32= (float*)   (ws + 4518032);   // 106392 f32 -> 4943600
  float4*   w3      = (float4*)  (ws + 4943600);   // 2304 float4 -> 4980464
  double*   Weff    = (double*)  (ws + 4980464);   // 2304*16 f64 -> 5275376
  double*   Wpart   = (double*)  (ws + 5275376);   // 16*2304*16 f64 -> 9993968
  uint32_t* alist   = (uint32_t*)(ws + 9993968);   // 8192 u32 -> 10026736
  double*   ssort   = (double*)  (ws + 10026736);  // 6016 f64 -> 10074864
  double*   sbx     = (double*)  (ws + 10074864);  // 6016*4 f64 -> 10267376
  float4*   bxf     = (float4*)  (ws + 10267376);  // 6016 float4 -> 10363632
  float*    areaf   = (float*)   (ws + 10363632);  // 6016 f32 -> 10387696
  uint64_t* Sup     = (uint64_t*)(ws + 10387696);  // 6016*96 u64 -> 15007984
  uint64_t* pkey    = (uint64_t*)(ws + 15007984);  // 8192 u64 -> 15073520
  uint32_t* rank32  = (uint32_t*)(ws + 15073520);  // 8192 u32 -> 15106288
  float* out = (float*)d_out;

  hipMemsetAsync(ws, 0, 262208, stream);             // hist + counters
  hipMemsetAsync(rank32, 0, 32768, stream);          // rank accumulators
  k_weff_part<<<144, 256, 0, stream>>>(cw, sw, bw, Wpart);
  k_weff_fin<<<10, 256, 0, stream>>>(Wpart, cb, sb, bb, sw, bw, Weff, fb, w3, fb32);
  k_fast<<<555, 256, 0, stream>>>(p0, p1, p2, p3, p4, w3, fb32, logits32, hist);
  k_edge<<<1, 1024, 0, stream>>>(hist, cnts);
  k_compact<<<416, 256, 0, stream>>>(logits32, cnts, alist);
  k_refine<<<128, 256, 0, stream>>>(p0, p1, p2, p3, p4, Weff, fb, alist, cnts,
                                    logits, deltas, pkey);
  k_rank_cnt<<<512, 256, 0, stream>>>(cnts, pkey, rank32);
  k_scatter<<<32, 256, 0, stream>>>(cnts, pkey, rank32, logits, deltas, im_info,
                                    ssort, sbx, bxf, areaf);
  k_build<<<94 * 24, 256, 0, stream>>>(sbx, bxf, areaf, Sup);
  k_scan<<<1, 256, 0, stream>>>(Sup, ssort, sbx, out);
}

// Round 12
// 492.534 us; speedup vs baseline: 1.5894x; 1.1728x over previous
//
#include <hip/hip_runtime.h>
#include <stdint.h>

#define N_ANCH   106392
#define PRE_NMS  6000
#define POST_NMS 1000
#define POOL_CAP 8192
#define NMS_BLKS 94   // 94*64 = 6016 >= 6000
#define SUP_W    96   // padded words per suppression row

static __device__ const int    LV_H[5]      = {128, 64, 32, 16, 8};
static __device__ const int    LV_W[5]      = {208, 104, 52, 26, 13};
static __device__ const int    LV_STRIDE[5] = {4, 8, 16, 32, 64};
static __device__ const int    LV_PIX[5]    = {26624, 6656, 1664, 416, 104};
static __device__ const int    LV_TILE0[6]  = {0, 416, 520, 546, 553, 555};
static __device__ const int    LV_AOFF[6]   = {0, 79872, 99840, 104832, 106080, 106392};
static __device__ const int    GPOFF[6]     = {0, 26624, 33280, 34944, 35360, 35464};
// Base anchors computed with np.round (half-even) semantics, verified by hand.
static __device__ const double BASE_ANCH[5][3][4] = {
  {{-22.,-10.,25.,13.},   {-14.,-14.,17.,17.},    {-10.,-22.,13.,25.}},
  {{-40.,-20.,47.,27.},   {-28.,-28.,35.,35.},    {-20.,-44.,27.,51.}},
  {{-84.,-40.,99.,55.},   {-56.,-56.,71.,71.},    {-36.,-80.,51.,95.}},
  {{-164.,-72.,195.,103.},{-112.,-112.,143.,143.},{-76.,-168.,107.,199.}},
  {{-332.,-152.,395.,215.},{-224.,-224.,287.,287.},{-148.,-328.,211.,391.}}
};

// sortable mappings (monotone): bigger value -> bigger key
__device__ __forceinline__ uint32_t sort32f(float f) {
  uint32_t u = __float_as_uint(f);
  return ((int)u < 0) ? ~u : (u | 0x80000000u);
}
__device__ __forceinline__ uint64_t sort64(double d) {
  uint64_t u = (uint64_t)__double_as_longlong(d);
  return ((long long)u < 0) ? ~u : (u | 0x8000000000000000ull);
}

// ---------------- f64 effective weights, 2-stage ----------------
// comb inline: j<3 -> sw[3+j][c]-sw[j][c]; 3<=j<15 -> bw[j-3][c]
__device__ __forceinline__ double combf(const float* sw, const float* bw, int c, int j) {
  if (j < 3) return (double)sw[(3 + j) * 512 + c] - (double)sw[j * 512 + c];
  return (double)bw[(j - 3) * 512 + c];
}

__global__ __launch_bounds__(256) void k_weff_part(const float* __restrict__ cw,
                                                   const float* __restrict__ sw,
                                                   const float* __restrict__ bw,
                                                   double* __restrict__ Wpart) {
  int chunk = blockIdx.x / 9;            // 16 chunks of 32 channels
  int tb = blockIdx.x % 9;               // 9 t-blocks of 256
  int t = tb * 256 + threadIdx.x;        // 0..2303
  int c0 = chunk * 32;
  double acc[15];
#pragma unroll
  for (int j = 0; j < 15; ++j) acc[j] = 0.0;
#pragma unroll 1
  for (int c = c0; c < c0 + 32; ++c) {
    double v = (double)cw[c * 2304 + t];
#pragma unroll
    for (int j = 0; j < 15; ++j) acc[j] += v * combf(sw, bw, c, j);
  }
  double* o = Wpart + (((size_t)chunk * 2304 + t) << 4);
#pragma unroll
  for (int j = 0; j < 15; ++j) o[j] = acc[j];
  o[15] = 0.0;
}

// blocks 0..8: Weff[t][j] = sum over chunks; also emit f32 screen weights w3.
// block 9: fb f64 + fb32.
__global__ __launch_bounds__(256) void k_weff_fin(const double* __restrict__ Wpart,
                                                  const float* __restrict__ cb,
                                                  const float* __restrict__ sb,
                                                  const float* __restrict__ bb,
                                                  const float* __restrict__ sw,
                                                  const float* __restrict__ bw,
                                                  double* __restrict__ Weff,
                                                  double* __restrict__ fb,
                                                  float4* __restrict__ w3,
                                                  float* __restrict__ fb32) {
  if (blockIdx.x == 9) {
    __shared__ double ps[15][16];
    int tid = threadIdx.x;
    if (tid < 240) {
      int j = tid >> 4, part = tid & 15;
      double s = 0.0;
      for (int c = part * 32; c < part * 32 + 32; ++c)
        s += (double)cb[c] * combf(sw, bw, c, j);
      ps[j][part] = s;
    }
    __syncthreads();
    if (tid < 15) {
      double s = 0.0;
#pragma unroll
      for (int part = 0; part < 16; ++part) s += ps[tid][part];  // fixed order
      s += (tid < 3) ? ((double)sb[3 + tid] - (double)sb[tid]) : (double)bb[tid - 3];
      fb[tid] = s;
      if (tid < 3) fb32[tid] = (float)s;
    }
    if (tid == 15) fb32[3] = 0.f;
    return;
  }
  int t = blockIdx.x * 256 + threadIdx.x;
  double acc[15];
#pragma unroll
  for (int j = 0; j < 15; ++j) acc[j] = 0.0;
#pragma unroll 1
  for (int chunk = 0; chunk < 16; ++chunk) {
    const double* p = Wpart + (((size_t)chunk * 2304 + t) << 4);
#pragma unroll
    for (int j = 0; j < 15; ++j) acc[j] += p[j];
  }
  double* o = Weff + ((size_t)t << 4);
#pragma unroll
  for (int j = 0; j < 15; ++j) o[j] = acc[j];
  o[15] = 0.0;
  float4 wf;
  wf.x = (float)acc[0]; wf.y = (float)acc[1]; wf.z = (float)acc[2]; wf.w = 0.f;
  w3[t] = wf;
}

// ---------------- f32 screening pass: 3 logits/pixel + histogram ----------------
__device__ __forceinline__ void load9(float v[9], const float* __restrict__ ib,
                                      const bool rok[3], const bool cok[3],
                                      const int roff[3]) {
#pragma unroll
  for (int ky = 0; ky < 3; ++ky)
#pragma unroll
    for (int kx = 0; kx < 3; ++kx)
      v[ky * 3 + kx] = (rok[ky] && cok[kx]) ? ib[roff[ky] + kx] : 0.0f;
}

__global__ __launch_bounds__(256) void k_fast(
    const float* __restrict__ p0, const float* __restrict__ p1,
    const float* __restrict__ p2, const float* __restrict__ p3,
    const float* __restrict__ p4,
    const float4* __restrict__ w3, const float* __restrict__ fb32,
    float* __restrict__ logits32, uint32_t* __restrict__ hist) {
  __shared__ float4 w3s[2304];       // 36.9 KB, LDS-resident weights
  __shared__ float red[4][64][3];
  int tid = threadIdx.x, wv = tid >> 6, ln = tid & 63;
  for (int i = tid; i < 2304; i += 256) w3s[i] = w3[i];
  int t = blockIdx.x;
  int L = 0;
  while (L < 4 && t >= LV_TILE0[L + 1]) ++L;
  const float* inL = (L == 0) ? p0 : (L == 1) ? p1 : (L == 2) ? p2 : (L == 3) ? p3 : p4;
  int H = LV_H[L], W = LV_W[L], HW = H * W, PIX = LV_PIX[L];
  int pix = (t - LV_TILE0[L]) * 64 + ln;
  bool valid = pix < PIX;
  if (!valid) pix = PIX - 1;
  int h = pix / W, w = pix % W;
  bool rok[3], cok[3];
  int roff[3];
#pragma unroll
  for (int ky = 0; ky < 3; ++ky) {
    int iy = h + ky - 1;
    rok[ky] = (iy >= 0 && iy < H);
    roff[ky] = iy * W + w - 1;
  }
#pragma unroll
  for (int kx = 0; kx < 3; ++kx) {
    int ix = w + kx - 1;
    cok[kx] = (ix >= 0 && ix < W);
  }
  __syncthreads();
  float a0 = 0.f, a1 = 0.f, a2 = 0.f;
  int ci0 = wv * 64;
  const float* ib = inL + ci0 * HW;
#pragma unroll 1
  for (int ci = ci0; ci < ci0 + 64; ++ci, ib += HW) {
    float v[9];
    load9(v, ib, rok, cok, roff);
    const float4* wr = w3s + ci * 9;
#pragma unroll
    for (int t9 = 0; t9 < 9; ++t9) {
      float4 wt = wr[t9];                  // broadcast ds_read_b128
      float vv = v[t9];
      a0 += vv * wt.x; a1 += vv * wt.y; a2 += vv * wt.z;
    }
  }
  red[wv][ln][0] = a0; red[wv][ln][1] = a1; red[wv][ln][2] = a2;
  __syncthreads();
  if (wv == 0 && valid) {
    int gbase = LV_AOFF[L] + pix * 3;
#pragma unroll
    for (int a = 0; a < 3; ++a) {
      float f = (red[0][ln][a] + red[1][ln][a]) + (red[2][ln][a] + red[3][ln][a]);
      f += fb32[a];
      logits32[gbase + a] = f;
      atomicAdd(&hist[sort32f(f) >> 16], 1u);
    }
  }
}

// ---------------- edge finder (with 2-bin safety margin) ----------------
__global__ __launch_bounds__(1024) void k_edge(const uint32_t* __restrict__ hist,
                                               uint32_t* __restrict__ cnts) {
  __shared__ uint32_t cs[1024];
  __shared__ uint32_t g_grp, g_suf;
  int t = threadIdx.x, wv = t >> 6, ln = t & 63;
#pragma unroll 4
  for (int r = 0; r < 64; ++r) {
    int g = r * 16 + wv;
    uint32_t x = hist[g * 64 + ln];
#pragma unroll
    for (int off = 32; off > 0; off >>= 1) x += __shfl_down(x, off);
    if (ln == 0) cs[g] = x;
  }
  __syncthreads();
  for (int off = 1; off < 1024; off <<= 1) {
    uint32_t v = cs[t] + ((t + off < 1024) ? cs[t + off] : 0u);
    __syncthreads();
    cs[t] = v;
    __syncthreads();
  }
  uint32_t sufnext = (t < 1023) ? cs[t + 1] : 0u;
  if (cs[t] >= PRE_NMS && sufnext < PRE_NMS) {   // unique t
    g_grp = (uint32_t)t;
    g_suf = sufnext;
  }
  __syncthreads();
  if (t < 64) {   // wave 0: refine edge within the winning 64-bin group
    uint32_t grp = g_grp, suf = g_suf;
    uint32_t x = hist[grp * 64 + t];
    uint32_t S = x;
#pragma unroll
    for (int off = 1; off < 64; off <<= 1) {
      uint32_t y = __shfl_down(S, off);
      if (t + off < 64) S += y;
    }
    unsigned long long mask = __ballot(suf + S >= PRE_NMS);
    int hi = 63 - (int)__clzll(mask);
    if (t == hi) {
      uint32_t e = grp * 64 + (uint32_t)hi;
      cnts[1] = (e > 2) ? e - 2 : 0;     // -2 bin margin: f32 superset of f64 top-k
    }
  }
}

// ---------------- pool compaction (f32 screen) ----------------
__global__ __launch_bounds__(256) void k_compact(const float* __restrict__ logits32,
                                                 uint32_t* __restrict__ cnts,
                                                 uint32_t* __restrict__ alist) {
  int i = blockIdx.x * 256 + threadIdx.x;
  if (i >= N_ANCH) return;
  if ((sort32f(logits32[i]) >> 16) >= cnts[1]) {
    uint32_t pos = atomicAdd(&cnts[0], 1u);
    if (pos < POOL_CAP) alist[pos] = (uint32_t)i;
  }
}

// ---------------- f64 refine: exact logit + deltas + sort key ----------------
__global__ __launch_bounds__(256) void k_refine(
    const float* __restrict__ p0, const float* __restrict__ p1,
    const float* __restrict__ p2, const float* __restrict__ p3,
    const float* __restrict__ p4,
    const double* __restrict__ Weff, const double* __restrict__ fb,
    const uint32_t* __restrict__ alist, const uint32_t* __restrict__ cnts,
    double* __restrict__ logits, double* __restrict__ deltas,
    uint64_t* __restrict__ pkey) {
  __shared__ double red[4][64][5];
  int tid = threadIdx.x, wv = tid >> 6, ln = tid & 63;
  int cnt = (int)cnts[0];
  if (cnt > POOL_CAP) cnt = POOL_CAP;
  int base = blockIdx.x * 64;
  if (base >= cnt) return;                 // uniform early-exit
  int slot = base + ln;
  if (slot >= cnt) slot = cnt - 1;         // dup tail (benign same-value writes)
  int gi = (int)alist[slot];
  int gpix = gi / 3, a = gi - gpix * 3;
  int L = 0;
  while (L < 4 && gpix >= GPOFF[L + 1]) ++L;
  int pix = gpix - GPOFF[L];
  const float* inL = (L == 0) ? p0 : (L == 1) ? p1 : (L == 2) ? p2 : (L == 3) ? p3 : p4;
  int H = LV_H[L], W = LV_W[L], HW = H * W;
  int h = pix / W, w = pix % W;
  bool rok[3], cok[3];
  int roff[3];
#pragma unroll
  for (int ky = 0; ky < 3; ++ky) {
    int iy = h + ky - 1;
    rok[ky] = (iy >= 0 && iy < H);
    roff[ky] = iy * W + w - 1;
  }
#pragma unroll
  for (int kx = 0; kx < 3; ++kx) {
    int ix = w + kx - 1;
    cok[kx] = (ix >= 0 && ix < W);
  }
  double sc = 0.0, d0 = 0.0, d1 = 0.0, d2 = 0.0, d3 = 0.0;
  int js = a, jd = 3 + 4 * a;
  int ci0 = wv * 64;
  const float* ib = inL + ci0 * HW;
#pragma unroll 1
  for (int ci = ci0; ci < ci0 + 64; ++ci, ib += HW) {
    float v[9];
    load9(v, ib, rok, cok, roff);
    const double* wr = Weff + ((size_t)ci * 144);
#pragma unroll
    for (int t9 = 0; t9 < 9; ++t9) {
      double vd = (double)v[t9];
      const double* wt = wr + t9 * 16;
      sc += vd * wt[js];
      d0 += vd * wt[jd + 0];
      d1 += vd * wt[jd + 1];
      d2 += vd * wt[jd + 2];
      d3 += vd * wt[jd + 3];
    }
  }
  red[wv][ln][0] = sc;
  red[wv][ln][1] = d0; red[wv][ln][2] = d1;
  red[wv][ln][3] = d2; red[wv][ln][4] = d3;
  __syncthreads();
  if (wv == 0) {
    double f[5];
#pragma unroll
    for (int j = 0; j < 5; ++j)
      f[j] = red[0][ln][j] + red[1][ln][j] + red[2][ln][j] + red[3][ln][j];
    double lg = f[0] + fb[js];
    logits[gi] = lg;
    deltas[gi * 4 + 0] = f[1] + fb[jd + 0];
    deltas[gi * 4 + 1] = f[2] + fb[jd + 1];
    deltas[gi * 4 + 2] = f[3] + fb[jd + 2];
    deltas[gi * 4 + 3] = f[4] + fb[jd + 3];
    // top-47 bits of sortable f64 logit; low 17 bits inverted index ->
    // rank-descending breaks score ties by ascending index (top_k semantics)
    pkey[slot] = (sort64(lg) & ~0x1FFFFull) | (uint64_t)(0x1FFFFu - (uint32_t)gi);
  }
}

// ---------------- 2D rank-by-counting: 32 i-tiles x 16 j-chunks ----------------
// rank32[e] += #{j in chunk : pkey[j] > pkey[e]}  (u32 atomics: exact, commutative)
__global__ __launch_bounds__(256) void k_rank_cnt(const uint32_t* __restrict__ cnts,
                                                  const uint64_t* __restrict__ pkey,
                                                  uint32_t* __restrict__ rank32) {
  __shared__ uint64_t lk[512];
  int t = threadIdx.x;
  int cnt = (int)cnts[0];
  if (cnt > POOL_CAP) cnt = POOL_CAP;
  int it = blockIdx.x >> 4, jc = blockIdx.x & 15;
  int e = it * 256 + t;
  int c0 = jc * 512;
  if (it * 256 >= cnt || c0 >= cnt) return;   // uniform early-exit
  int lim = cnt - c0; if (lim > 512) lim = 512;
  for (int i = t; i < 512; i += 256) lk[i] = (i < lim) ? pkey[c0 + i] : 0ull;
  __syncthreads();
  bool active = e < cnt;
  uint64_t mykey = active ? pkey[e] : ~0ull;   // ~0 counts nothing
  int r = 0;
#pragma unroll 8
  for (int j = 0; j < 512; ++j) r += (lk[j] > mykey) ? 1 : 0;
  if (active && r) atomicAdd(&rank32[e], (uint32_t)r);
}

// ---------------- scatter by rank + box decode ----------------
__global__ __launch_bounds__(256) void k_scatter(const uint32_t* __restrict__ cnts,
                                                 const uint64_t* __restrict__ pkey,
                                                 const uint32_t* __restrict__ rank32,
                                                 const double* __restrict__ logits,
                                                 const double* __restrict__ deltas,
                                                 const float* __restrict__ im_info,
                                                 double* __restrict__ ss,
                                                 double* __restrict__ sbx,
                                                 float4* __restrict__ bxf,
                                                 float* __restrict__ areaf) {
  int t = threadIdx.x;
  int cnt = (int)cnts[0];
  if (cnt > POOL_CAP) cnt = POOL_CAP;
  int e = blockIdx.x * 256 + t;
  if (blockIdx.x * 256 >= cnt) return;     // uniform
  if (e >= cnt) return;
  int rank = (int)rank32[e];
  if (rank >= PRE_NMS) return;
  uint64_t mykey = pkey[e];
  int gi = 0x1FFFF - (int)(mykey & 0x1FFFFull);
  int L = 0;
  while (L < 4 && gi >= LV_AOFF[L + 1]) ++L;
  int rel = gi - LV_AOFF[L];
  int pix = rel / 3, a = rel % 3;
  int W = LV_W[L];
  int h = pix / W, w = pix % W;
  double imW1 = (double)im_info[1] - 1.0;
  double imH1 = (double)im_info[0] - 1.0;
  double shx = (double)(w * LV_STRIDE[L]), shy = (double)(h * LV_STRIDE[L]);
  double ax1 = BASE_ANCH[L][a][0] + shx, ay1 = BASE_ANCH[L][a][1] + shy;
  double ax2 = BASE_ANCH[L][a][2] + shx, ay2 = BASE_ANCH[L][a][3] + shy;
  double dx = deltas[gi * 4 + 0], dy = deltas[gi * 4 + 1];
  double dw = deltas[gi * 4 + 2], dh = deltas[gi * 4 + 3];
  double wa = ax2 - ax1 + 1.0, ha = ay2 - ay1 + 1.0;
  double cx = ax1 + 0.5 * wa, cy = ay1 + 0.5 * ha;
  double pcx = dx * wa + cx, pcy = dy * ha + cy;
  double pw = exp(dw) * wa, ph = exp(dh) * ha;
  double x1 = fmin(fmax(pcx - 0.5 * pw, 0.0), imW1);
  double y1 = fmin(fmax(pcy - 0.5 * ph, 0.0), imH1);
  double x2 = fmin(fmax(pcx + 0.5 * pw, 0.0), imW1);
  double y2 = fmin(fmax(pcy + 0.5 * ph, 0.0), imH1);
  ss[rank] = 1.0 / (1.0 + exp(-logits[gi]));
  sbx[rank * 4 + 0] = x1; sbx[rank * 4 + 1] = y1;
  sbx[rank * 4 + 2] = x2; sbx[rank * 4 + 3] = y2;
  float4 bf;
  bf.x = (float)x1; bf.y = (float)y1; bf.z = (float)x2; bf.w = (float)y2;
  bxf[rank] = bf;
  areaf[rank] = (float)((x2 - x1 + 1.0) * (y2 - y1 + 1.0));
}

// ---------------- exact f64 IoU decision (reference semantics) ----------------
__device__ __forceinline__ bool iou_gt(const double* A, const double* B) {
  double areaA = (A[2] - A[0] + 1.0) * (A[3] - A[1] + 1.0);
  double areaB = (B[2] - B[0] + 1.0) * (B[3] - B[1] + 1.0);
  double xx1 = fmax(A[0], B[0]), yy1 = fmax(A[1], B[1]);
  double xx2 = fmin(A[2], B[2]), yy2 = fmin(A[3], B[3]);
  double iw = fmax(0.0, xx2 - xx1 + 1.0), ih = fmax(0.0, yy2 - yy1 + 1.0);
  double inter = iw * ih;
  return inter > 0.7 * (areaA + areaB - inter);
}

// ---------------- suppression matrix build (upper triangle) ----------------
// Sup[r][w] bit jj set  <=>  IoU(box r, box w*64+jj) > 0.7, for j > r.
// f32 prefilter with +-4.0 absolute margin on (inter - 0.7*union); f64 confirm
// in the gray zone -> decisions identical to pure f64. Rows/cols >= PRE_NMS
// may read unwritten (poisoned) staging rows; their bits are masked in k_scan.
__global__ __launch_bounds__(256) void k_build(const double* __restrict__ sbx,
                                               const float4* __restrict__ bxf,
                                               const float* __restrict__ areaf,
                                               uint64_t* __restrict__ Sup) {
  __shared__ float cbx[256][5];
  __shared__ float rbx[64][5];
  int blk = blockIdx.x;
  int rtile = blk / 24, ctile = blk % 24;   // 94 x 24
  int t = threadIdx.x, q = t >> 6, ln = t & 63;
  int r = rtile * 64 + ln;
  int w = ctile * 4 + q;                    // word 0..95
  {
    int c = ctile * 256 + t;
    float4 b;
    float ar;
    if (c < NMS_BLKS * 64) { b = bxf[c]; ar = areaf[c]; }
    else { b.x = b.y = b.z = b.w = 0.f; ar = 0.f; }
    cbx[t][0] = b.x; cbx[t][1] = b.y; cbx[t][2] = b.z; cbx[t][3] = b.w; cbx[t][4] = ar;
    if (t < 64) {
      int rr = rtile * 64 + t;
      float4 rb = bxf[rr];
      rbx[t][0] = rb.x; rbx[t][1] = rb.y; rbx[t][2] = rb.z; rbx[t][3] = rb.w;
      rbx[t][4] = areaf[rr];
    }
  }
  __syncthreads();
  uint64_t bits = 0ull;
  int j0 = w * 64;
  if (w < NMS_BLKS && j0 + 63 > r) {
    float ax1 = rbx[ln][0], ay1 = rbx[ln][1], ax2 = rbx[ln][2], ay2 = rbx[ln][3];
    float aar = rbx[ln][4];
#pragma unroll 4
    for (int jj = 0; jj < 64; ++jj) {
      int j = j0 + jj;
      if (j <= r) continue;
      int cl = q * 64 + jj;
      float iw = fminf(ax2, cbx[cl][2]) - fmaxf(ax1, cbx[cl][0]) + 1.f;
      float ih = fminf(ay2, cbx[cl][3]) - fmaxf(ay1, cbx[cl][1]) + 1.f;
      float inter = fmaxf(iw, 0.f) * fmaxf(ih, 0.f);
      float d = inter - 0.7f * (aar + cbx[cl][4] - inter);
      bool sup;
      if (d > 4.0f) sup = true;
      else if (d < -4.0f) sup = false;
      else sup = iou_gt(sbx + (size_t)r * 4, sbx + (size_t)j * 4);  // rare
      if (sup) bits |= 1ull << jj;
    }
  }
  Sup[(size_t)r * SUP_W + w] = bits;
}

// ---------------- parallel-OR incremental greedy NMS scan ----------------
// ext masks accumulate in a pre-zeroed LDS array ext_arr[94][2]; per block:
// wave 0 scans (diagonal prefetched), then ALL 1024 threads OR kept rows'
// word b+1 (1 gathered load/thread, latencies overlap) via wave-reduce +
// 4 LDS atomicOr. 2 barriers/block (R8 had 3 + two-stage reduce; R10/R11's
// single-wave OR serialized the load latencies).
__global__ __launch_bounds__(1024) void k_scan(const uint64_t* __restrict__ Sup,
                                               const double* __restrict__ ss,
                                               const double* __restrict__ sbx,
                                               float* __restrict__ out) {
  __shared__ uint16_t keep[POST_NMS];
  __shared__ uint32_t ext_arr[NMS_BLKS][2];
  __shared__ int s_kcnt;
  int t = threadIdx.x, wv = t >> 6, ln = t & 63;
  for (int i = t; i < NMS_BLKS * 2; i += 1024) ext_arr[i >> 1][i & 1] = 0u;
  if (t == 0) s_kcnt = 0;
  uint64_t nrow = 0ull;
  if (wv == 0) nrow = Sup[(size_t)ln * SUP_W];   // prefetch block 0 diagonal
  __syncthreads();
  for (int b = 0; b < NMS_BLKS; ++b) {
    if (wv == 0) {   // wave 0: scan with accumulated ext; prefetch next diag
      uint64_t myrow = nrow & ~((2ull << ln) - 1ull);
      if (b + 1 < NMS_BLKS)
        nrow = Sup[(size_t)((b + 1) * 64 + ln) * SUP_W + (b + 1)];
      uint64_t ext = ((uint64_t)ext_arr[b][1] << 32) | ext_arr[b][0];
      int base = b * 64;
      if (base + 63 >= PRE_NMS) {
        int v = PRE_NMS - base;                // 48 for the tail block
        ext |= ~((1ull << v) - 1ull);
      }
      int K0 = s_kcnt;
      uint64_t avail = ~ext;
      uint64_t kp = 0ull;
      int lim = POST_NMS - K0, nk = 0;
      while (avail && nk < lim) {
        int i2 = __ffsll((unsigned long long)avail) - 1;
        kp |= 1ull << i2;
        ++nk;
        uint64_t row = __shfl(myrow, i2);
        avail &= ~row;
        avail &= ~(1ull << i2);
      }
      if ((kp >> ln) & 1ull) {
        int pos = K0 + __popcll(kp & ((1ull << ln) - 1ull));
        keep[pos] = (uint16_t)(base + ln);
      }
      if (ln == 0) s_kcnt = K0 + nk;
    }
    __syncthreads();
    int K = s_kcnt;
    if (K >= POST_NMS || b + 1 >= NMS_BLKS) break;  // OR phase useless
    // build ext for block b+1: OR word b+1 of all kept rows (1 load/thread)
    uint64_t m = 0ull;
    for (int p = t; p < K; p += 1024) m |= Sup[(size_t)keep[p] * SUP_W + (b + 1)];
#pragma unroll
    for (int off = 32; off > 0; off >>= 1) m |= __shfl_down(m, off);
    if (ln == 0 && m) {
      uint32_t lo = (uint32_t)m, hi = (uint32_t)(m >> 32);
      if (lo) atomicOr(&ext_arr[b + 1][0], lo);
      if (hi) atomicOr(&ext_arr[b + 1][1], hi);
    }
    __syncthreads();
  }
  __syncthreads();
  int KF = s_kcnt;
  for (int r = t; r < POST_NMS; r += 1024) {
    float* o = out + r * 6;
    if (r < KF) {
      int p = keep[r];
      o[0] = 0.f;
      o[1] = (float)sbx[p * 4 + 0];
      o[2] = (float)sbx[p * 4 + 1];
      o[3] = (float)sbx[p * 4 + 2];
      o[4] = (float)sbx[p * 4 + 3];
      o[5] = (float)ss[p];
    } else {
#pragma unroll
      for (int c = 0; c < 6; ++c) o[c] = 0.f;
    }
  }
}

// ---------------- host launch ----------------
extern "C" void kernel_launch(void* const* d_in, const int* in_sizes, int n_in,
                              void* d_out, int out_size, void* d_ws, size_t ws_size,
                              hipStream_t stream) {
  const float* p0 = (const float*)d_in[0];
  const float* p1 = (const float*)d_in[1];
  const float* p2 = (const float*)d_in[2];
  const float* p3 = (const float*)d_in[3];
  const float* p4 = (const float*)d_in[4];
  const float* im_info = (const float*)d_in[5];
  const float* cw = (const float*)d_in[6];
  const float* cb = (const float*)d_in[7];
  const float* sw = (const float*)d_in[8];
  const float* sb = (const float*)d_in[9];
  const float* bw = (const float*)d_in[10];
  const float* bb = (const float*)d_in[11];
  char* ws = (char*)d_ws;
  // ws layout (bytes):
  uint32_t* hist    = (uint32_t*)(ws + 0);         // 65536 u32 -> 262144
  uint32_t* cnts    = (uint32_t*)(ws + 262144);    // [0]=pool [1]=edge -> 262208
  double*   fb      = (double*)  (ws + 262208);    // 16 f64 -> 262336
  float*    fb32    = (float*)   (ws + 262336);    // 4 f32  -> 262352
  double*   logits  = (double*)  (ws + 262352);    // 106392 f64 -> 1113488
  double*   deltas  = (double*)  (ws + 1113488);   // 425568 f64 -> 4518032
  float*    logits32= (float*)   (ws + 4518032);   // 106392 f32 -> 4943600
  float4*   w3      = (float4*)  (ws + 4943600);   // 2304 float4 -> 4980464
  double*   Weff    = (double*)  (ws + 4980464);   // 2304*16 f64 -> 5275376
  double*   Wpart   = (double*)  (ws + 5275376);   // 16*2304*16 f64 -> 9993968
  uint32_t* alist   = (uint32_t*)(ws + 9993968);   // 8192 u32 -> 10026736
  double*   ssort   = (double*)  (ws + 10026736);  // 6016 f64 -> 10074864
  double*   sbx     = (double*)  (ws + 10074864);  // 6016*4 f64 -> 10267376
  float4*   bxf     = (float4*)  (ws + 10267376);  // 6016 float4 -> 10363632
  float*    areaf   = (float*)   (ws + 10363632);  // 6016 f32 -> 10387696
  uint64_t* Sup     = (uint64_t*)(ws + 10387696);  // 6016*96 u64 -> 15007984
  uint64_t* pkey    = (uint64_t*)(ws + 15007984);  // 8192 u64 -> 15073520
  uint32_t* rank32  = (uint32_t*)(ws + 15073520);  // 8192 u32 -> 15106288
  float* out = (float*)d_out;

  hipMemsetAsync(ws, 0, 262208, stream);             // hist + counters
  hipMemsetAsync(rank32, 0, 32768, stream);          // rank accumulators
  k_weff_part<<<144, 256, 0, stream>>>(cw, sw, bw, Wpart);
  k_weff_fin<<<10, 256, 0, stream>>>(Wpart, cb, sb, bb, sw, bw, Weff, fb, w3, fb32);
  k_fast<<<555, 256, 0, stream>>>(p0, p1, p2, p3, p4, w3, fb32, logits32, hist);
  k_edge<<<1, 1024, 0, stream>>>(hist, cnts);
  k_compact<<<416, 256, 0, stream>>>(logits32, cnts, alist);
  k_refine<<<128, 256, 0, stream>>>(p0, p1, p2, p3, p4, Weff, fb, alist, cnts,
                                    logits, deltas, pkey);
  k_rank_cnt<<<512, 256, 0, stream>>>(cnts, pkey, rank32);
  k_scatter<<<32, 256, 0, stream>>>(cnts, pkey, rank32, logits, deltas, im_info,
                                    ssort, sbx, bxf, areaf);
  k_build<<<94 * 24, 256, 0, stream>>>(sbx, bxf, areaf, Sup);
  k_scan<<<1, 1024, 0, stream>>>(Sup, ssort, sbx, out);
}